// Round 4
// baseline (5070.298 us; speedup 1.0000x reference)
//
#include <hip/hip_runtime.h>

// ---------- constants ----------
#define B_   64
#define P_   196
#define ENC_ 512
#define ATT_ 256
#define DEC_ 256
#define EMB_ 256
#define V_   10000
#define T_   44
#define G4_  1024          // 4*DEC
#define XW_  768           // ENC+EMB (W_ih inner dim)
#define PP_  208           // padded P for bf16 att1 rows
// X fragment-major layout per group: [parity][hi/lo][chunk=24][b16][32k] shorts
#define XGRP 49152         // shorts per group (2 parity * 2 hilo * 12288)
#define XPARS 24576        // shorts per parity (hi+lo)
#define XHL  12288         // shorts per hi or lo plane

using short8 = __attribute__((ext_vector_type(8))) short;
using f32x4  = __attribute__((ext_vector_type(4))) float;

__device__ __forceinline__ unsigned short f2bf(float f) {
    unsigned int u = __float_as_uint(f);
    unsigned int r = (u + 0x7fffu + ((u >> 16) & 1u)) >> 16;
    return (unsigned short)r;
}
__device__ __forceinline__ float bf2f(unsigned short h) {
    return __uint_as_float(((unsigned int)h) << 16);
}
// frag-major X index for a 16-batch group: k in [0,768), bl in [0,16)
__device__ __forceinline__ int xidx16(int bl, int k) {
    return ((k >> 5) << 9) + (bl << 5) + (k & 31);
}

// ---------- generic 32x32 transpose: dst[k*N + n] = src[n*stride + off + k] ----------
__global__ void k_transpose(const float* __restrict__ src, float* __restrict__ dst,
                            int N, int stride, int off) {
    __shared__ float t[32][33];
    int k0 = blockIdx.x * 32, n0 = blockIdx.y * 32;
    int tx = threadIdx.x & 31, ty = threadIdx.x >> 5;
    for (int r = ty; r < 32; r += 8)
        t[r][tx] = src[(size_t)(n0 + r) * stride + off + k0 + tx];
    __syncthreads();
    for (int r = ty; r < 32; r += 8)
        dst[(size_t)(k0 + r) * N + n0 + tx] = t[tx][r];
}

// ---------- fp32 -> bf16 convert ----------
__global__ void k_cvt(const float* __restrict__ src, unsigned short* __restrict__ dst, int n) {
    int i = blockIdx.x * 256 + threadIdx.x;
    if (i < n) dst[i] = f2bf(src[i]);
}

// ---------- permuted hi/lo gate weights: rows j' = d*4+gate, cols k (ctx 0..511, h 512..767)
__global__ __launch_bounds__(256) void k_prepW(
        const float* __restrict__ W_ih, const float* __restrict__ W_hh,
        unsigned short* __restrict__ Wgh, unsigned short* __restrict__ Wgl) {
    int jp = blockIdx.x;             // j' in [0,1024)
    int d = jp >> 2, gate = jp & 3;
    int j = gate * 256 + d;          // original row
    for (int kk = 0; kk < 3; kk++) {
        int k = threadIdx.x + 256 * kk;
        float w = (k < ENC_) ? W_ih[(size_t)j * XW_ + k]
                             : W_hh[(size_t)j * DEC_ + (k - ENC_)];
        unsigned short hi = f2bf(w);
        Wgh[(size_t)jp * XW_ + k] = hi;
        Wgl[(size_t)jp * XW_ + k] = f2bf(w - bf2f(hi));
    }
}

// ---------- h0/c0 from mean-pooled encoder; also seeds X parity-0 h-columns ----------
__global__ __launch_bounds__(256) void k_init_state(
        const float* __restrict__ enc,
        const float* __restrict__ W_init_h, const float* __restrict__ b_init_h,
        const float* __restrict__ W_init_c, const float* __restrict__ b_init_c,
        float* __restrict__ hbuf, float* __restrict__ c0buf,
        unsigned short* __restrict__ Xg) {
    int b = blockIdx.x, tid = threadIdx.x;
    __shared__ float avg[ENC_];
    for (int e = tid; e < ENC_; e += 256) {
        float s = 0.f;
        const float* p = enc + (size_t)b * P_ * ENC_ + e;
        for (int i = 0; i < P_; i++) s += p[(size_t)i * ENC_];
        avg[e] = s * (1.0f / (float)P_);
    }
    __syncthreads();
    int d = tid;
    float hs = b_init_h[d], cs = b_init_c[d];
    const float* wh = W_init_h + (size_t)d * ENC_;
    const float* wc = W_init_c + (size_t)d * ENC_;
    for (int e = 0; e < ENC_; e++) { float a = avg[e]; hs += a * wh[e]; cs += a * wc[e]; }
    hbuf[b * DEC_ + d] = hs;
    c0buf[b * DEC_ + d] = cs;
    // seed X parity 0 h-part (bf16 hi/lo, frag-major)
    int bg = b >> 4, bl = b & 15;
    unsigned short* Xh0 = Xg + (size_t)bg * XGRP;      // parity 0 hi
    unsigned short* Xl0 = Xh0 + XHL;
    int k = ENC_ + d;
    unsigned short hi = f2bf(hs);
    Xh0[xidx16(bl, k)] = hi;
    Xl0[xidx16(bl, k)] = f2bf(hs - bf2f(hi));
}

// ---------- att1bf[b][a][208pad] bf16 = enc[b] @ W_enc_att^T ----------
__global__ __launch_bounds__(256) void k_att1(
        const float* __restrict__ enc, const float* __restrict__ Wea,
        unsigned short* __restrict__ att1bf) {
    int b = blockIdx.x >> 2, a0 = (blockIdx.x & 3) * 64;
    __shared__ float encT[32][257];
    __shared__ float Wt[64][32];
    int tid = threadIdx.x;
    int pl = tid & 63, ia = tid >> 6;
    float acc[16][4];
#pragma unroll
    for (int k = 0; k < 16; k++)
#pragma unroll
        for (int q = 0; q < 4; q++) acc[k][q] = 0.f;

    for (int e0 = 0; e0 < ENC_; e0 += 32) {
        {
            int j = tid & 31, pr = tid >> 5;
            for (int pass = 0; pass < 32; pass++) {
                int p = pr + pass * 8;
                float v = 0.f;
                if (p < P_) v = enc[((size_t)b * P_ + p) * ENC_ + e0 + j];
                encT[j][p] = v;
            }
            int r = tid >> 2, c0 = (tid & 3) * 8;
#pragma unroll
            for (int i = 0; i < 8; i++)
                Wt[r][c0 + i] = Wea[(size_t)(a0 + r) * ENC_ + e0 + c0 + i];
        }
        __syncthreads();
        for (int e = 0; e < 32; e++) {
            float e0v = encT[e][pl], e1v = encT[e][pl + 64];
            float e2v = encT[e][pl + 128], e3v = encT[e][pl + 192];
#pragma unroll
            for (int k = 0; k < 16; k++) {
                float w = Wt[ia * 16 + k][e];
                acc[k][0] += w * e0v; acc[k][1] += w * e1v;
                acc[k][2] += w * e2v; acc[k][3] += w * e3v;
            }
        }
        __syncthreads();
    }
#pragma unroll
    for (int k = 0; k < 16; k++)
#pragma unroll
        for (int q = 0; q < 4; q++) {
            int p = pl + 64 * q;
            if (p < P_)
                att1bf[(size_t)b * (ATT_ * PP_) + (size_t)(a0 + ia * 16 + k) * PP_ + p] =
                    f2bf(acc[k][q]);
        }
}

// ---------- embW[(t*64+b)][j'] with j' = d*4+gate (permuted), includes biases ----------
__global__ __launch_bounds__(256) void k_embW(
        const int* __restrict__ caption, const float* __restrict__ embedding,
        const float* __restrict__ WiheT, const float* __restrict__ b_ih,
        const float* __restrict__ b_hh, float* __restrict__ embW) {
    int r0 = blockIdx.x * 16, tid = threadIdx.x;
    __shared__ float embL[16][256];
    __shared__ int capL[16];
    if (tid < 16) {
        int r = r0 + tid, t = r >> 6, b = r & 63;
        capL[tid] = caption[b * T_ + t];
    }
    __syncthreads();
#pragma unroll
    for (int lr = 0; lr < 16; lr++)
        embL[lr][tid] = embedding[(size_t)capL[lr] * EMB_ + tid];
    __syncthreads();
    float base0 = b_ih[tid] + b_hh[tid];
    float base1 = b_ih[tid + 256] + b_hh[tid + 256];
    float base2 = b_ih[tid + 512] + b_hh[tid + 512];
    float base3 = b_ih[tid + 768] + b_hh[tid + 768];
    float acc[16][4];
#pragma unroll
    for (int lr = 0; lr < 16; lr++) {
        acc[lr][0] = base0; acc[lr][1] = base1; acc[lr][2] = base2; acc[lr][3] = base3;
    }
    for (int e = 0; e < EMB_; e++) {
        const float* wr = WiheT + (size_t)e * G4_ + tid;
        float w0 = wr[0], w1 = wr[256], w2 = wr[512], w3 = wr[768];
#pragma unroll
        for (int lr = 0; lr < 16; lr++) {
            float ev = embL[lr][e];
            acc[lr][0] += w0 * ev; acc[lr][1] += w1 * ev;
            acc[lr][2] += w2 * ev; acc[lr][3] += w3 * ev;
        }
    }
#pragma unroll
    for (int lr = 0; lr < 16; lr++) {
        float4 st = make_float4(acc[lr][0], acc[lr][1], acc[lr][2], acc[lr][3]);
        *reinterpret_cast<float4*>(&embW[(size_t)(r0 + lr) * G4_ + tid * 4]) = st;
    }
}

// ---------- group-local epoch-flag barrier (64 blocks per group) ----------
__device__ __forceinline__ void groupbar(unsigned* gf, unsigned it, int myslot) {
    __syncthreads();
    __threadfence();
    if (threadIdx.x == 0)
        __hip_atomic_store(&gf[myslot], it, __ATOMIC_RELAXED, __HIP_MEMORY_SCOPE_AGENT);
    if (threadIdx.x < 64) {
        for (;;) {
            unsigned v = __hip_atomic_load(&gf[threadIdx.x], __ATOMIC_RELAXED,
                                           __HIP_MEMORY_SCOPE_AGENT);
            if (v >= it) break;
            __builtin_amdgcn_s_sleep(2);
        }
    }
    __threadfence();
    __syncthreads();
}

// ---------- persistent recurrence: 4 independent groups of 64 blocks ----------
// group bg = g>>6 owns batches [16bg, 16bg+16); js = g&63 owns j' rows [16js,16js+16).
// P1 (all): b1 = 16bg + (js&15), ctx-quarter q1 = js>>4.
// P2 (all): 16b x 16j' MFMA tile, k split across 4 waves, group-local X ping-pong.
__global__ __launch_bounds__(256) void k_recur_coop(
        const float* __restrict__ enc, const unsigned short* __restrict__ att1bf,
        const float* __restrict__ WdaT, const float* __restrict__ W_full,
        const unsigned short* __restrict__ Wgh, const unsigned short* __restrict__ Wgl,
        const float* __restrict__ embW, float* __restrict__ hbuf,
        const float* __restrict__ c0buf, unsigned short* __restrict__ Xg,
        unsigned short* __restrict__ Hbf, float* __restrict__ out_alpha,
        unsigned* __restrict__ flags) {
    const int g = blockIdx.x, tid = threadIdx.x;
    const int bg = g >> 6, js = g & 63;
    const int b1 = 16 * bg + (js & 15), q1 = js >> 4;
    const int lane = tid & 63, w = tid >> 6;
    unsigned* gf = flags + bg * 64;

    __shared__ __align__(16) unsigned short WLh_l[16 * 776];
    __shared__ __align__(16) unsigned short WLl_l[16 * 776];
    __shared__ float scratch[1024];            // att2 partials / ctx partials
    __shared__ float wf_l[256], h_l[256], att2_l[256], alpha_l[256];
    __shared__ float red_l[8];
    __shared__ float gates_l[4 * 320];         // [wave][16b][20]

    // ---- prologue (no grid sync needed; producers are prior kernels) ----
    wf_l[tid] = W_full[tid];
    for (int i = tid; i < 1536; i += 256) {
        int r = i / 96, cp = (i % 96) * 8;
        *reinterpret_cast<uint4*>(&WLh_l[r * 776 + cp]) =
            *reinterpret_cast<const uint4*>(&Wgh[(size_t)(16 * js + r) * XW_ + cp]);
        *reinterpret_cast<uint4*>(&WLl_l[r * 776 + cp]) =
            *reinterpret_cast<const uint4*>(&Wgl[(size_t)(16 * js + r) * XW_ + cp]);
    }
    float c = 0.f;
    if (tid < 64) {
        int bl = tid >> 2, dl = tid & 3;
        c = c0buf[(16 * bg + bl) * DEC_ + 4 * js + dl];
    }

    const unsigned short* a1row = att1bf + (size_t)b1 * (ATT_ * PP_) + tid;
    const float* encb = enc + (size_t)b1 * P_ * ENC_;
    unsigned short* XgG = Xg + (size_t)bg * XGRP;
    unsigned it = 1;

    for (int t = 0; t < T_; t++) {
        unsigned short* Xh_t = XgG + (size_t)(t & 1) * XPARS;
        unsigned short* Xl_t = Xh_t + XHL;
        unsigned short* Xh_n = XgG + (size_t)((t + 1) & 1) * XPARS;
        unsigned short* Xl_n = Xh_n + XHL;

        // ================= PHASE 1 =================
        h_l[tid] = hbuf[b1 * DEC_ + tid];
        __syncthreads();
        // att2: wave w covers d in [64w,64w+64); lane owns a = 4*lane..4*lane+4
        {
            const float* wp = WdaT + (size_t)(64 * w) * ATT_ + 4 * lane;
            float a0 = 0.f, a1 = 0.f, a2 = 0.f, a3 = 0.f;
#pragma unroll 8
            for (int i = 0; i < 64; i++) {
                float hv = h_l[64 * w + i];
                float4 wv = *reinterpret_cast<const float4*>(wp + (size_t)i * ATT_);
                a0 += wv.x * hv; a1 += wv.y * hv; a2 += wv.z * hv; a3 += wv.w * hv;
            }
            float4 st = make_float4(a0, a1, a2, a3);
            *reinterpret_cast<float4*>(&scratch[w * 256 + 4 * lane]) = st;
        }
        __syncthreads();
        att2_l[tid] = scratch[tid] + scratch[256 + tid] + scratch[512 + tid] + scratch[768 + tid];
        __syncthreads();
        // scores + softmax (thread = p)
        {
            float s = -1e30f;
            if (tid < P_) {
                float s0 = 0.f, s1 = 0.f, s2 = 0.f, s3 = 0.f;
                float s4 = 0.f, s5 = 0.f, s6 = 0.f, s7 = 0.f;
                for (int a = 0; a < ATT_; a += 8) {
                    float v0 = bf2f(a1row[(a + 0) * PP_]) + att2_l[a + 0];
                    float v1 = bf2f(a1row[(a + 1) * PP_]) + att2_l[a + 1];
                    float v2 = bf2f(a1row[(a + 2) * PP_]) + att2_l[a + 2];
                    float v3 = bf2f(a1row[(a + 3) * PP_]) + att2_l[a + 3];
                    float v4 = bf2f(a1row[(a + 4) * PP_]) + att2_l[a + 4];
                    float v5 = bf2f(a1row[(a + 5) * PP_]) + att2_l[a + 5];
                    float v6 = bf2f(a1row[(a + 6) * PP_]) + att2_l[a + 6];
                    float v7 = bf2f(a1row[(a + 7) * PP_]) + att2_l[a + 7];
                    s0 += fmaxf(v0, 0.f) * wf_l[a + 0];
                    s1 += fmaxf(v1, 0.f) * wf_l[a + 1];
                    s2 += fmaxf(v2, 0.f) * wf_l[a + 2];
                    s3 += fmaxf(v3, 0.f) * wf_l[a + 3];
                    s4 += fmaxf(v4, 0.f) * wf_l[a + 4];
                    s5 += fmaxf(v5, 0.f) * wf_l[a + 5];
                    s6 += fmaxf(v6, 0.f) * wf_l[a + 6];
                    s7 += fmaxf(v7, 0.f) * wf_l[a + 7];
                }
                s = ((s0 + s1) + (s2 + s3)) + ((s4 + s5) + (s6 + s7));
            }
            float m = s;
#pragma unroll
            for (int off = 32; off; off >>= 1) m = fmaxf(m, __shfl_xor(m, off));
            if (lane == 0) red_l[w] = m;
            __syncthreads();
            m = fmaxf(fmaxf(red_l[0], red_l[1]), fmaxf(red_l[2], red_l[3]));
            float ex = (tid < P_) ? __expf(s - m) : 0.f;
            float sm = ex;
#pragma unroll
            for (int off = 32; off; off >>= 1) sm += __shfl_xor(sm, off);
            if (lane == 0) red_l[4 + w] = sm;
            __syncthreads();
            sm = red_l[4] + red_l[5] + red_l[6] + red_l[7];
            float alpha = ex / sm;
            alpha_l[tid] = alpha;
            if (q1 == 0 && tid < P_)
                out_alpha[(size_t)b1 * (T_ * P_) + t * P_ + tid] = alpha;
        }
        __syncthreads();
        // ctx e-quarter -> X[t&1] ctx columns (bf16 hi/lo, frag-major)
        {
            int el = tid & 127, ph = tid >> 7;
            int e = q1 * 128 + el;
            float cx = 0.f;
            const float* ep = encb + (size_t)(98 * ph) * ENC_ + e;
#pragma unroll 2
            for (int p = 0; p < 98; p++)
                cx += alpha_l[98 * ph + p] * ep[(size_t)p * ENC_];
            scratch[tid] = cx;
            __syncthreads();
            if (tid < 128) {
                float v = scratch[tid] + scratch[tid + 128];
                int k = q1 * 128 + tid;
                int xi = xidx16(b1 & 15, k);
                unsigned short hi = f2bf(v);
                Xh_t[xi] = hi;
                Xl_t[xi] = f2bf(v - bf2f(hi));
            }
        }
        groupbar(gf, it++, js);

        // ================= PHASE 2 =================
        // wave w: k-chunks [6w, 6w+6); 16b x 16j' tile; hi/lo split => 3 MFMAs
        {
            const unsigned short* xh = Xh_t + ((lane & 15) << 5) + ((lane >> 4) << 3);
            const unsigned short* xl = Xl_t + ((lane & 15) << 5) + ((lane >> 4) << 3);
            const unsigned short* bhp = &WLh_l[(lane & 15) * 776 + ((lane >> 4) << 3)];
            const unsigned short* blp = &WLl_l[(lane & 15) * 776 + ((lane >> 4) << 3)];
            f32x4 acc = {0.f, 0.f, 0.f, 0.f};
#pragma unroll
            for (int ci = 0; ci < 6; ci++) {
                int cc = 6 * w + ci;
                short8 ah = *reinterpret_cast<const short8*>(xh + cc * 512);
                short8 al = *reinterpret_cast<const short8*>(xl + cc * 512);
                short8 bh = *reinterpret_cast<const short8*>(bhp + cc * 32);
                short8 bl = *reinterpret_cast<const short8*>(blp + cc * 32);
                acc = __builtin_amdgcn_mfma_f32_16x16x32_bf16(ah, bh, acc, 0, 0, 0);
                acc = __builtin_amdgcn_mfma_f32_16x16x32_bf16(al, bh, acc, 0, 0, 0);
                acc = __builtin_amdgcn_mfma_f32_16x16x32_bf16(ah, bl, acc, 0, 0, 0);
            }
            int col = lane & 15, rb = (lane >> 4) * 4;
#pragma unroll
            for (int r = 0; r < 4; r++)
                gates_l[w * 320 + (rb + r) * 20 + col] = acc[r];
        }
        __syncthreads();
        // pointwise: threads 0..63: (bl = tid>>2, dl = tid&3) -> d = 4js+dl
        if (tid < 64) {
            int bl = tid >> 2, dl = tid & 3;
            float4 s0 = *reinterpret_cast<const float4*>(&gates_l[0 * 320 + bl * 20 + dl * 4]);
            float4 s1 = *reinterpret_cast<const float4*>(&gates_l[1 * 320 + bl * 20 + dl * 4]);
            float4 s2 = *reinterpret_cast<const float4*>(&gates_l[2 * 320 + bl * 20 + dl * 4]);
            float4 s3 = *reinterpret_cast<const float4*>(&gates_l[3 * 320 + bl * 20 + dl * 4]);
            int b_glob = 16 * bg + bl;
            int d = 4 * js + dl;
            float4 ee = *reinterpret_cast<const float4*>(
                &embW[((size_t)t * B_ + b_glob) * G4_ + 16 * js + dl * 4]);
            float g0 = s0.x + s1.x + s2.x + s3.x + ee.x;
            float g1 = s0.y + s1.y + s2.y + s3.y + ee.y;
            float g2 = s0.z + s1.z + s2.z + s3.z + ee.z;
            float g3 = s0.w + s1.w + s2.w + s3.w + ee.w;
            float i_g = 1.f / (1.f + __expf(-g0));
            float f_g = 1.f / (1.f + __expf(-g1));
            float g_g = tanhf(g2);
            float o_g = 1.f / (1.f + __expf(-g3));
            c = f_g * c + i_g * g_g;
            float hn = o_g * tanhf(c);
            hbuf[b_glob * DEC_ + d] = hn;
            int k = ENC_ + d;
            int xi = xidx16(bl, k);
            unsigned short hi = f2bf(hn);
            Xh_n[xi] = hi;
            Xl_n[xi] = f2bf(hn - bf2f(hi));
            Hbf[((size_t)t * B_ + b_glob) * DEC_ + d] = f2bf(hn);
        }
        groupbar(gf, it++, js);
    }
}

// ---------- logits: bf16 MFMA ----------
__global__ __launch_bounds__(256) void k_logits(
        const unsigned short* __restrict__ Hbf, const unsigned short* __restrict__ Woutbf,
        const float* __restrict__ b_out, float* __restrict__ out) {
    int n0 = blockIdx.x * 128, m0 = blockIdx.y * 128;
    __shared__ __align__(16) unsigned short At[128][40];
    __shared__ __align__(16) unsigned short Bt[128][40];
    int tid = threadIdx.x;
    int lane = tid & 63, w = tid >> 6;
    int wm = (w & 1) * 64, wn = (w >> 1) * 64;
    f32x4 acc[4][4];
#pragma unroll
    for (int i = 0; i < 4; i++)
#pragma unroll
        for (int j = 0; j < 4; j++) acc[i][j] = (f32x4){0.f, 0.f, 0.f, 0.f};

    for (int k0 = 0; k0 < DEC_; k0 += 32) {
#pragma unroll
        for (int l = 0; l < 2; l++) {
            int idx = l * 256 + tid;
            int r = idx >> 2, kc = (idx & 3) * 8;
            uint4 av = *reinterpret_cast<const uint4*>(&Hbf[(size_t)(m0 + r) * DEC_ + k0 + kc]);
            *reinterpret_cast<uint4*>(&At[r][kc]) = av;
            uint4 bv = make_uint4(0u, 0u, 0u, 0u);
            if (n0 + r < V_)
                bv = *reinterpret_cast<const uint4*>(&Woutbf[(size_t)(n0 + r) * DEC_ + k0 + kc]);
            *reinterpret_cast<uint4*>(&Bt[r][kc]) = bv;
        }
        __syncthreads();
        int qk = (lane >> 4) * 8, fr = lane & 15;
        short8 a[4], bb[4];
#pragma unroll
        for (int i = 0; i < 4; i++) {
            a[i]  = *reinterpret_cast<const short8*>(&At[wm + i * 16 + fr][qk]);
            bb[i] = *reinterpret_cast<const short8*>(&Bt[wn + i * 16 + fr][qk]);
        }
#pragma unroll
        for (int i = 0; i < 4; i++)
#pragma unroll
            for (int j = 0; j < 4; j++)
                acc[i][j] = __builtin_amdgcn_mfma_f32_16x16x32_bf16(a[i], bb[j], acc[i][j], 0, 0, 0);
        __syncthreads();
    }
    int col = lane & 15, qr = (lane >> 4) * 4;
#pragma unroll
    for (int j = 0; j < 4; j++) {
        int n = n0 + wn + j * 16 + col;
        if (n < V_) {
            float bo = b_out[n];
#pragma unroll
            for (int i = 0; i < 4; i++)
#pragma unroll
                for (int r = 0; r < 4; r++) {
                    int m = m0 + wm + i * 16 + qr + r;
                    int t = m >> 6, b = m & 63;
                    out[(size_t)b * (T_ * V_) + (size_t)t * V_ + n] = acc[i][j][r] + bo;
                }
        }
    }
}

// ---------- launch ----------
extern "C" void kernel_launch(void* const* d_in, const int* in_sizes, int n_in,
                              void* d_out, int out_size, void* d_ws, size_t ws_size,
                              hipStream_t stream) {
    const float* enc       = (const float*)d_in[0];
    const int*   caption   = (const int*)d_in[1];
    const float* W_enc_att = (const float*)d_in[2];
    const float* W_dec_att = (const float*)d_in[3];
    const float* W_full    = (const float*)d_in[4];
    const float* embedding = (const float*)d_in[5];
    const float* W_init_h  = (const float*)d_in[6];
    const float* b_init_h  = (const float*)d_in[7];
    const float* W_init_c  = (const float*)d_in[8];
    const float* b_init_c  = (const float*)d_in[9];
    const float* W_ih      = (const float*)d_in[10];
    const float* b_ih      = (const float*)d_in[11];
    const float* W_hh      = (const float*)d_in[12];
    const float* b_hh      = (const float*)d_in[13];
    const float* W_out     = (const float*)d_in[14];
    const float* b_out     = (const float*)d_in[15];

    float* ws = (float*)d_ws;
    unsigned* flags = (unsigned*)ws;                         // 256 uints
    float* c0buf    = ws + 256;          // 16384
    float* WdaT     = ws + 16640;        // 65536  [d][a] fp32
    float* hbuf     = ws + 82176;        // 16384
    float* embW     = ws + 98560;        // 2883584 [t*64+b][j'] fp32 (biases included)
    unsigned short* att1bf = (unsigned short*)(ws + 2982144); // 64*256*208 shorts
    unsigned short* Wgh    = (unsigned short*)(ws + 4686080); // 1024x768 shorts
    unsigned short* Wgl    = (unsigned short*)(ws + 5079296); // 1024x768 shorts
    unsigned short* Xg     = (unsigned short*)(ws + 5472512); // 4 groups x 49152 shorts
    unsigned short* Hbf    = (unsigned short*)(ws + 5570816); // 2816x256 shorts
    unsigned short* Woutbf = (unsigned short*)(ws + 5931264); // 10000x256 shorts
    float* WiheT    = ws + 5931264;      // aliases Woutbf; dead before k_cvt(W_out)

    float* out_pred  = (float*)d_out;
    float* out_alpha = out_pred + (size_t)B_ * T_ * V_;

    hipMemsetAsync(flags, 0, 1024, stream);
    k_transpose<<<dim3(8, 8),  256, 0, stream>>>(W_dec_att, WdaT, ATT_, DEC_, 0);
    k_transpose<<<dim3(8, 32), 256, 0, stream>>>(W_ih, WiheT, G4_, XW_, ENC_);
    k_prepW<<<1024, 256, 0, stream>>>(W_ih, W_hh, Wgh, Wgl);
    k_init_state<<<B_, 256, 0, stream>>>(enc, W_init_h, b_init_h, W_init_c, b_init_c,
                                         hbuf, c0buf, Xg);
    k_att1<<<B_ * 4, 256, 0, stream>>>(enc, W_enc_att, att1bf);
    k_embW<<<176, 256, 0, stream>>>(caption, embedding, WiheT, b_ih, b_hh, embW);
    k_cvt<<<10000, 256, 0, stream>>>(W_out, Woutbf, V_ * DEC_);   // after k_embW (alias)
    k_recur_coop<<<256, 256, 0, stream>>>(enc, att1bf, WdaT, W_full, Wgh, Wgl, embW,
                                          hbuf, c0buf, Xg, Hbf, out_alpha, flags);
    k_logits<<<dim3(79, 22), 256, 0, stream>>>(Hbf, Woutbf, b_out, out_pred);
}